// Round 18
// baseline (190.754 us; speedup 1.0000x reference)
//
#include <hip/hip_runtime.h>

#define DEVINL __device__ __forceinline__

// 3-level a-trous B3-spline UWT, fused single kernel.
// WIDE-LANE TILE (work-cut, committed path after the round-13 occupancy
// probe proved throughput-bound): each lane owns 8 cols (lo/hi float4),
// so a 16-lane DPP group spans 128 staged cols -> 96 output cols.
// X overhead 2.0x -> 1.33x; total conv work -22%, staging -13%.
// Tile 96x32 (ragged last X tile: 64 cols). LDS (60+56)x132x4 = 59.8 KB
// -> 2 blocks/CU (8 waves). Body = two independent copies of the proven
// slim 5-read strided pipeline per row (same-row, no cross-row deps).

constexpr int W_IMG = 1024;
constexpr int H_IMG = 1024;
constexpr int TXO = 96;                   // output cols per full tile
constexpr int TY = 32;                    // output rows per tile (GYT exact)
constexpr int HALO = 16;                  // >= 14 (2*(1+2+4))
constexpr int SW = 132;                   // LDS row stride floats (128+4 pad)
constexpr int GXT = 11;                   // 10 full tiles + 1 ragged (64 cols)
constexpr int GYT = 32;
constexpr int SHA = 60;                   // A slots: input rows 2..61
constexpr int SHB = 56;                   // B slots: L0 rows 4..59

constexpr float TP0 = 1.0f / 16.0f;
constexpr float TP1 = 1.0f / 4.0f;
constexpr float TP2 = 3.0f / 8.0f;

typedef float f32x4 __attribute__((ext_vector_type(4)));

// DPP within 16-lane rows: row_shr:1 (0x111) = lane i-1's value (0 at lane 0),
// row_shl:1 (0x101) = lane i+1's value (0 at lane 15). Zeros land only in
// halo cols: chain gives valid staged cols 14..113 at L2; outputs 16..111.
template <int CTRL>
DEVINL float dppf(float x) {
    return __int_as_float(__builtin_amdgcn_update_dpp(
        0, __float_as_int(x), CTRL, 0xF, 0xF, true));
}

DEVINL int reflx(int g) {
    g = g < 0 ? -g : g;
    return g >= W_IMG ? 2 * W_IMG - 2 - g : g;
}

DEVINL void nt_store4(float* p, float a, float b, float c, float d) {
    f32x4 t;
    t.x = a; t.y = b; t.z = c; t.w = d;
    __builtin_nontemporal_store(t, (f32x4*)p);
}

DEVINL float4 ld4(const float* p) { return *(const float4*)p; }

DEVINL float4 vert(const float4& a0, const float4& a1, const float4& a2,
                   const float4& a3, const float4& a4) {
    float4 v;
    v.x = TP0 * (a0.x + a4.x) + TP1 * (a1.x + a3.x) + TP2 * a2.x;
    v.y = TP0 * (a0.y + a4.y) + TP1 * (a1.y + a3.y) + TP2 * a2.y;
    v.z = TP0 * (a0.z + a4.z) + TP1 * (a1.z + a3.z) + TP2 * a2.z;
    v.w = TP0 * (a0.w + a4.w) + TP1 * (a1.w + a3.w) + TP2 * a2.w;
    return v;
}

// 8-col horizontal 5-tap. lane owns cols 8p..8p+7 (vlo, vhi).
template <int D>
DEVINL void horiz8(const float4& vlo, const float4& vhi, float4& ulo,
                   float4& uhi) {
    if constexpr (D == 1) {
        const float pHz = dppf<0x111>(vhi.z);  // col 8p-2
        const float pHw = dppf<0x111>(vhi.w);  // col 8p-1
        const float nLx = dppf<0x101>(vlo.x);  // col 8p+8
        const float nLy = dppf<0x101>(vlo.y);  // col 8p+9
        ulo.x = TP0 * (pHz + vlo.z) + TP1 * (pHw + vlo.y) + TP2 * vlo.x;
        ulo.y = TP0 * (pHw + vlo.w) + TP1 * (vlo.x + vlo.z) + TP2 * vlo.y;
        ulo.z = TP0 * (vlo.x + vhi.x) + TP1 * (vlo.y + vlo.w) + TP2 * vlo.z;
        ulo.w = TP0 * (vlo.y + vhi.y) + TP1 * (vlo.z + vhi.x) + TP2 * vlo.w;
        uhi.x = TP0 * (vlo.z + vhi.z) + TP1 * (vlo.w + vhi.y) + TP2 * vhi.x;
        uhi.y = TP0 * (vlo.w + vhi.w) + TP1 * (vhi.x + vhi.z) + TP2 * vhi.y;
        uhi.z = TP0 * (vhi.x + nLx) + TP1 * (vhi.y + vhi.w) + TP2 * vhi.z;
        uhi.w = TP0 * (vhi.y + nLy) + TP1 * (vhi.z + nLx) + TP2 * vhi.w;
    } else if constexpr (D == 2) {  // taps +-2, +-4
        const float pHx = dppf<0x111>(vhi.x);  // 8p-4
        const float pHy = dppf<0x111>(vhi.y);  // 8p-3
        const float pHz = dppf<0x111>(vhi.z);  // 8p-2
        const float pHw = dppf<0x111>(vhi.w);  // 8p-1
        const float nLx = dppf<0x101>(vlo.x);  // 8p+8
        const float nLy = dppf<0x101>(vlo.y);  // 8p+9
        const float nLz = dppf<0x101>(vlo.z);  // 8p+10
        const float nLw = dppf<0x101>(vlo.w);  // 8p+11
        ulo.x = TP0 * (pHx + vhi.x) + TP1 * (pHz + vlo.z) + TP2 * vlo.x;
        ulo.y = TP0 * (pHy + vhi.y) + TP1 * (pHw + vlo.w) + TP2 * vlo.y;
        ulo.z = TP0 * (pHz + vhi.z) + TP1 * (vlo.x + vhi.x) + TP2 * vlo.z;
        ulo.w = TP0 * (pHw + vhi.w) + TP1 * (vlo.y + vhi.y) + TP2 * vlo.w;
        uhi.x = TP0 * (vlo.x + nLx) + TP1 * (vlo.z + vhi.z) + TP2 * vhi.x;
        uhi.y = TP0 * (vlo.y + nLy) + TP1 * (vlo.w + vhi.w) + TP2 * vhi.y;
        uhi.z = TP0 * (vlo.z + nLz) + TP1 * (vhi.x + nLx) + TP2 * vhi.z;
        uhi.w = TP0 * (vlo.w + nLw) + TP1 * (vhi.y + nLy) + TP2 * vhi.w;
    } else {  // D == 4: taps +-4, +-8 — per-component, +-1 lane reg pairs
        float4 pL, pH, nL, nH;
        pL.x = dppf<0x111>(vlo.x); pL.y = dppf<0x111>(vlo.y);
        pL.z = dppf<0x111>(vlo.z); pL.w = dppf<0x111>(vlo.w);  // 8p-8+j
        pH.x = dppf<0x111>(vhi.x); pH.y = dppf<0x111>(vhi.y);
        pH.z = dppf<0x111>(vhi.z); pH.w = dppf<0x111>(vhi.w);  // 8p-4+j
        nL.x = dppf<0x101>(vlo.x); nL.y = dppf<0x101>(vlo.y);
        nL.z = dppf<0x101>(vlo.z); nL.w = dppf<0x101>(vlo.w);  // 8p+8+j
        nH.x = dppf<0x101>(vhi.x); nH.y = dppf<0x101>(vhi.y);
        nH.z = dppf<0x101>(vhi.z); nH.w = dppf<0x101>(vhi.w);  // 8p+12+j
        ulo.x = TP0 * (pL.x + nL.x) + TP1 * (pH.x + vhi.x) + TP2 * vlo.x;
        ulo.y = TP0 * (pL.y + nL.y) + TP1 * (pH.y + vhi.y) + TP2 * vlo.y;
        ulo.z = TP0 * (pL.z + nL.z) + TP1 * (pH.z + vhi.z) + TP2 * vlo.z;
        ulo.w = TP0 * (pL.w + nL.w) + TP1 * (pH.w + vhi.w) + TP2 * vlo.w;
        uhi.x = TP0 * (pH.x + nH.x) + TP1 * (vlo.x + nL.x) + TP2 * vhi.x;
        uhi.y = TP0 * (pH.y + nH.y) + TP1 * (vlo.y + nL.y) + TP2 * vhi.y;
        uhi.z = TP0 * (pH.z + nH.z) + TP1 * (vlo.z + nL.z) + TP2 * vhi.z;
        uhi.w = TP0 * (pH.w + nH.w) + TP1 * (vlo.w + nL.w) + TP2 * vhi.w;
    }
}

// Strided level, 8 cols/lane. src slot = r-SOFF, dst slot = r-DOFF.
// 10 independent ds_read_b128 per row (2 per tap, lo/hi).
template <int D, int R0, int R1, int SOFF, int DOFF, int LVL, bool LAST,
          bool GUARD>
DEVINL void do_level(const float* src, float* dst, float* obase, bool pok,
                     int ty, int c8) {
    constexpr size_t PL = (size_t)H_IMG * W_IMG;
    constexpr int KMAX = (R1 - R0 + 15) / 16;
#pragma unroll 2
    for (int k = 0; k < KMAX; ++k) {
        const int r = R0 + ty + 16 * k;
        if (!GUARD || r < R1) {  // uniform per 16-lane DPP row
            const float* bp = &src[(r - SOFF) * SW + c8];
            const float4 l0 = ld4(bp - 2 * D * SW);
            const float4 h0 = ld4(bp - 2 * D * SW + 4);
            const float4 l1 = ld4(bp - D * SW);
            const float4 h1 = ld4(bp - D * SW + 4);
            const float4 l2 = ld4(bp);
            const float4 h2 = ld4(bp + 4);
            const float4 l3 = ld4(bp + D * SW);
            const float4 h3 = ld4(bp + D * SW + 4);
            const float4 l4 = ld4(bp + 2 * D * SW);
            const float4 h4 = ld4(bp + 2 * D * SW + 4);
            const float4 vlo = vert(l0, l1, l2, l3, l4);
            const float4 vhi = vert(h0, h1, h2, h3, h4);
            float4 ulo, uhi;
            horiz8<D>(vlo, vhi, ulo, uhi);
            const int ly = r - HALO;
            if (pok && (unsigned)ly < (unsigned)TY) {
                float* pw = obase + (size_t)LVL * PL + ((size_t)ly << 10);
                nt_store4(pw, l2.x - ulo.x, l2.y - ulo.y, l2.z - ulo.z,
                          l2.w - ulo.w);
                nt_store4(pw + 4, h2.x - uhi.x, h2.y - uhi.y, h2.z - uhi.z,
                          h2.w - uhi.w);
                if constexpr (LAST) {
                    float* pc = obase + (size_t)3 * PL + ((size_t)ly << 10);
                    nt_store4(pc, ulo.x, ulo.y, ulo.z, ulo.w);
                    nt_store4(pc + 4, uhi.x, uhi.y, uhi.z, uhi.w);
                }
            }
            if constexpr (!LAST) {
                *(float4*)&dst[(r - DOFF) * SW + c8] = ulo;
                *(float4*)&dst[(r - DOFF) * SW + c8 + 4] = uhi;
            }
        }
    }
}

__global__ __launch_bounds__(256, 2) void uwt3(const float* __restrict__ x,
                                               float* __restrict__ out) {
    __shared__ __align__(16) float A[SHA * SW];  // 31680 B
    __shared__ __align__(16) float B[SHB * SW];  // 29568 B; total 61248 B

    const int tid = threadIdx.x;
    const int p = tid & 15;
    const int ty = tid >> 4;
    const int bid = blockIdx.x;
    const int bx = bid % GXT;
    const int rest = bid / GXT;
    const int by = rest & 31;                 // GYT = 32 (pow2)
    const int b = rest >> 5;
    const int oy0 = by * TY;
    const int gx0 = bx * TXO;
    const float* xb = x + (size_t)b * (H_IMG * W_IMG);
    const int c8 = p * 8;
    const bool edge = (bx == 0) || (bx == GXT - 1);
    const int pmax = (bx == GXT - 1) ? 10 : 14;  // ragged last tile: 64 cols
    const bool pok = (p >= 2) && (p < pmax);
    // per-thread output base (deref'd only under pok; oy0+ly <= 1023 always)
    float* obase = out + ((size_t)(b * 4) * H_IMG + oy0) * W_IMG +
                   (gx0 - HALO + c8);

    // stage input rows 2..61 into A (slot = row-2), 8 cols/lane
#pragma unroll 2
    for (int k = 0; k < 4; ++k) {
        const int sr = 2 + ty + 16 * k;
        if (sr < 62) {
            int gy = oy0 - HALO + sr;
            gy = gy < 0 ? -gy : gy;
            if (gy >= H_IMG) gy = 2 * H_IMG - 2 - gy;
            const float* row = xb + (size_t)gy * W_IMG;
            const int gx = gx0 - HALO + c8;
            float4 vlo, vhi;
            if (!edge) {
                vlo = *(const float4*)(row + gx);
                vhi = *(const float4*)(row + gx + 4);
            } else {
                vlo.x = row[reflx(gx)];
                vlo.y = row[reflx(gx + 1)];
                vlo.z = row[reflx(gx + 2)];
                vlo.w = row[reflx(gx + 3)];
                vhi.x = row[reflx(gx + 4)];
                vhi.y = row[reflx(gx + 5)];
                vhi.z = row[reflx(gx + 6)];
                vhi.w = row[reflx(gx + 7)];
            }
            *(float4*)&A[(sr - 2) * SW + c8] = vlo;
            *(float4*)&A[(sr - 2) * SW + c8 + 4] = vhi;
        }
    }
    __syncthreads();

    // L0: rows 4..59 -> B (slot r-4); reads A rows 2..61 exactly
    do_level<1, 4, 60, 2, 4, 0, false, true>(A, B, obase, pok, ty, c8);
    __syncthreads();
    // L1: rows 8..55 -> A (slot r-8); reads B rows 4..59 exactly (48 = 3*16)
    do_level<2, 8, 56, 4, 8, 1, false, false>(B, A, obase, pok, ty, c8);
    __syncthreads();
    // L2: rows 16..47 exact output band; reads A(L1) rows 8..55 (32 = 2*16)
    do_level<4, 16, 48, 8, 0, 2, true, false>(A, B, obase, pok, ty, c8);
}

extern "C" void kernel_launch(void* const* d_in, const int* in_sizes, int n_in,
                              void* d_out, int out_size, void* d_ws,
                              size_t ws_size, hipStream_t stream) {
    const float* x = (const float*)d_in[0];
    float* out = (float*)d_out;
    const int nb = in_sizes[0] / (H_IMG * W_IMG);  // 8
    dim3 grid(nb * GYT * GXT);                     // 8*32*11 = 2816
    uwt3<<<grid, 256, 0, stream>>>(x, out);
}

// Round 19
// 179.521 us; speedup vs baseline: 1.0626x; 1.0626x over previous
//
#include <hip/hip_runtime.h>

#define DEVINL __device__ __forceinline__

// 3-level a-trous B3-spline UWT, fused single kernel.
// MEASURED-BEST variant (179.11 us total, kernel ~16.1 us): slim strided
// body, tile 32x64, LDS ping-pong, SW=68 pad. Five structural variants
// (rolling windows, pair/quad sharing, TY=32 occupancy, wide-lane 96x32,
// obase hoist) all measured neutral-to-worse; this is the local optimum.
//
// Tile: 32x64 output, staged 64x96 (halo 16 >= 14, 16B alignment).
// pack = tid&15 owns 4 consecutive cols (float4); ty = tid>>4 walks rows.
// Per level: vertical conv via 5 independent ds_read_b128 (compile-time
// offsets, good MLP), horizontal conv via DPP row_shr/row_shl (16 packs ==
// one 16-lane DPP row, edges align with halo).
// LDS ping-pong A<->B. 2 x 96 x 68 x 4 = 52.2 KB -> 3 blocks/CU.

constexpr int W_IMG = 1024;
constexpr int H_IMG = 1024;
constexpr int TX = 32;                    // output cols per tile
constexpr int TY = 64;                    // output rows per tile (GYT exact)
constexpr int HALO = 16;                  // >= 2*(1+2+4)=14
constexpr int SW = 68;                    // LDS row STRIDE in floats (64 + 4 pad)
constexpr int SH = TY + 2 * HALO;         // 96 staged rows
constexpr int GXT = W_IMG / TX;           // 32
constexpr int GYT = H_IMG / TY;           // 16 (exact)

constexpr float TP0 = 1.0f / 16.0f;
constexpr float TP1 = 1.0f / 4.0f;
constexpr float TP2 = 3.0f / 8.0f;

typedef float f32x4 __attribute__((ext_vector_type(4)));

// DPP cross-lane fetch within 16-lane rows. row_shr:n (0x110|n) = value from
// lane i-n; row_shl:n (0x100|n) = value from lane i+n. bound_ctrl=1 -> 0 at
// row edges (lands only in halo columns, never consumed by valid outputs).
template <int CTRL>
DEVINL float dppf(float x) {
    return __int_as_float(__builtin_amdgcn_update_dpp(
        0, __float_as_int(x), CTRL, 0xF, 0xF, true));
}

DEVINL int reflx(int g) {
    g = g < 0 ? -g : g;
    return g >= W_IMG ? 2 * W_IMG - 2 - g : g;
}

DEVINL void nt_store4(float* p, float a, float b, float c, float d) {
    f32x4 t;
    t.x = a; t.y = b; t.z = c; t.w = d;
    __builtin_nontemporal_store(t, (f32x4*)p);
}

// Row ranges are the EXACT dataflow need:
//   L2 (D=4) outputs rows 16..79  -> R0=16, R1=80
//   L1 (D=2) must cover 8..87     -> R0=8,  R1=88
//   L0 (D=1) must cover 4..91     -> R0=4,  R1=92
template <int D, int R0, int R1, int LVL, bool LAST>
DEVINL void do_level(const float* src, float* dst, float* __restrict__ out,
                     int b4, int oy0, int gx0, int p, int ty) {
    const int c4 = p * 4;
    constexpr int KMAX = (R1 - R0 + 15) / 16;
#pragma unroll 2
    for (int k = 0; k < KMAX; ++k) {
        const int r = R0 + ty + 16 * k;
        if (r < R1) {  // uniform across each 16-lane DPP row (same ty)
            const float4 a0 = *(const float4*)&src[(r - 2 * D) * SW + c4];
            const float4 a1 = *(const float4*)&src[(r - D) * SW + c4];
            const float4 a2 = *(const float4*)&src[r * SW + c4];
            const float4 a3 = *(const float4*)&src[(r + D) * SW + c4];
            const float4 a4 = *(const float4*)&src[(r + 2 * D) * SW + c4];
            // vertical 5-tap
            float4 v;
            v.x = TP0 * (a0.x + a4.x) + TP1 * (a1.x + a3.x) + TP2 * a2.x;
            v.y = TP0 * (a0.y + a4.y) + TP1 * (a1.y + a3.y) + TP2 * a2.y;
            v.z = TP0 * (a0.z + a4.z) + TP1 * (a1.z + a3.z) + TP2 * a2.z;
            v.w = TP0 * (a0.w + a4.w) + TP1 * (a1.w + a3.w) + TP2 * a2.w;
            // horizontal 5-tap via DPP neighbor exchange
            float4 u;
            if constexpr (D == 1) {
                const float am2 = dppf<0x111>(v.z);  // col-2 for comp0
                const float am1 = dppf<0x111>(v.w);  // col-1 for comp0
                const float ap1 = dppf<0x101>(v.x);  // col+1 for comp3
                const float ap2 = dppf<0x101>(v.y);  // col+2 for comp3
                u.x = TP0 * (am2 + v.z) + TP1 * (am1 + v.y) + TP2 * v.x;
                u.y = TP0 * (am1 + v.w) + TP1 * (v.x + v.z) + TP2 * v.y;
                u.z = TP0 * (v.x + ap1) + TP1 * (v.y + v.w) + TP2 * v.z;
                u.w = TP0 * (v.y + ap2) + TP1 * (v.z + ap1) + TP2 * v.w;
            } else if constexpr (D == 2) {
                u.x = TP0 * (dppf<0x111>(v.x) + dppf<0x101>(v.x)) +
                      TP1 * (dppf<0x111>(v.z) + v.z) + TP2 * v.x;
                u.y = TP0 * (dppf<0x111>(v.y) + dppf<0x101>(v.y)) +
                      TP1 * (dppf<0x111>(v.w) + v.w) + TP2 * v.y;
                u.z = TP0 * (dppf<0x111>(v.z) + dppf<0x101>(v.z)) +
                      TP1 * (v.x + dppf<0x101>(v.x)) + TP2 * v.z;
                u.w = TP0 * (dppf<0x111>(v.w) + dppf<0x101>(v.w)) +
                      TP1 * (v.y + dppf<0x101>(v.y)) + TP2 * v.w;
            } else {  // D == 4: pure per-component, +/-1 and +/-2 lanes
                u.x = TP0 * (dppf<0x112>(v.x) + dppf<0x102>(v.x)) +
                      TP1 * (dppf<0x111>(v.x) + dppf<0x101>(v.x)) + TP2 * v.x;
                u.y = TP0 * (dppf<0x112>(v.y) + dppf<0x102>(v.y)) +
                      TP1 * (dppf<0x111>(v.y) + dppf<0x101>(v.y)) + TP2 * v.y;
                u.z = TP0 * (dppf<0x112>(v.z) + dppf<0x102>(v.z)) +
                      TP1 * (dppf<0x111>(v.z) + dppf<0x101>(v.z)) + TP2 * v.z;
                u.w = TP0 * (dppf<0x112>(v.w) + dppf<0x102>(v.w)) +
                      TP1 * (dppf<0x111>(v.w) + dppf<0x101>(v.w)) + TP2 * v.w;
            }
            // w_LVL = c_{LVL-1} - c_LVL ; a2 is the center (prev) value
            const int ly = r - HALO;
            const int oy = oy0 + ly;
            if ((unsigned)ly < (unsigned)TY && p >= 4 && p < 12) {
                const int ox = gx0 + c4 - HALO;
                const size_t base =
                    ((size_t)(b4 + LVL) * H_IMG + oy) * W_IMG + ox;
                nt_store4(&out[base], a2.x - u.x, a2.y - u.y, a2.z - u.z,
                          a2.w - u.w);
                if constexpr (LAST) {
                    const size_t base3 =
                        ((size_t)(b4 + 3) * H_IMG + oy) * W_IMG + ox;
                    nt_store4(&out[base3], u.x, u.y, u.z, u.w);  // c_3
                }
            }
            if constexpr (!LAST) *(float4*)&dst[r * SW + c4] = u;
        }
    }
}

__global__ __launch_bounds__(256, 3) void uwt3(const float* __restrict__ x,
                                               float* __restrict__ out) {
    __shared__ __align__(16) float A[SH * SW];  // 26112 B
    __shared__ __align__(16) float B[SH * SW];  // total 52224 B -> 3 blk/CU

    const int tid = threadIdx.x;
    const int p = tid & 15;
    const int ty = tid >> 4;
    int bid = blockIdx.x;
    const int bx = bid & 31;  bid >>= 5;      // GXT = 32 (pow2)
    const int by = bid & 15;                  // GYT = 16 (pow2)
    const int b = bid >> 4;
    const int oy0 = by * TY;
    const int gx0 = bx * TX;
    const float* xb = x + (size_t)b * (H_IMG * W_IMG);
    const int c4 = p * 4;
    const bool edge = (bx == 0) || (bx == GXT - 1);

    // stage 64x96 input tile with reflect halo (SH = 96 = 6*16, no remainder)
#pragma unroll 2
    for (int k = 0; k < SH / 16; ++k) {
        const int sr = ty + 16 * k;
        int gy = oy0 - HALO + sr;
        gy = gy < 0 ? -gy : gy;
        if (gy >= H_IMG) gy = 2 * H_IMG - 2 - gy;
        const float* row = xb + (size_t)gy * W_IMG;
        const int gx = gx0 - HALO + c4;
        float4 v;
        if (!edge) {
            v = *(const float4*)(row + gx);
        } else {
            v.x = row[reflx(gx)];
            v.y = row[reflx(gx + 1)];
            v.z = row[reflx(gx + 2)];
            v.w = row[reflx(gx + 3)];
        }
        *(float4*)&A[sr * SW + c4] = v;
    }
    __syncthreads();

    do_level<1, 4, 92, 0, false>(A, B, out, b * 4, oy0, gx0, p, ty);
    __syncthreads();
    do_level<2, 8, 88, 1, false>(B, A, out, b * 4, oy0, gx0, p, ty);
    __syncthreads();
    do_level<4, 16, 80, 2, true>(A, B, out, b * 4, oy0, gx0, p, ty);
}

extern "C" void kernel_launch(void* const* d_in, const int* in_sizes, int n_in,
                              void* d_out, int out_size, void* d_ws,
                              size_t ws_size, hipStream_t stream) {
    const float* x = (const float*)d_in[0];
    float* out = (float*)d_out;
    const int nb = in_sizes[0] / (H_IMG * W_IMG);  // 8
    dim3 grid(nb * GYT * GXT);                     // 8*16*32 = 4096
    uwt3<<<grid, 256, 0, stream>>>(x, out);
}